// Round 1
// baseline (1500.857 us; speedup 1.0000x reference)
//
#include <hip/hip_runtime.h>

// GCN: N=100000 nodes, E=1600000 edges, 128 -> 16 -> 64 -> 128 -> 1
// Inputs (dict order): x[N,128] f32, edge_index[2,E] int32, W1[128,16], b1[16],
//   W2[16,64], b2[64], W3[64,128], b3[128], Wfc[128,1], bfc[1]
// Output: [N,1] f32.

#define NN 100000
#define NE 1600000

// ---------------- degree / norm ----------------
__global__ void deg_init_k(float* __restrict__ deg, int n) {
    int i = blockIdx.x * blockDim.x + threadIdx.x;
    if (i < n) deg[i] = 1.0f;  // self loop
}

__global__ void deg_count_k(const int* __restrict__ dst, float* __restrict__ deg, int e) {
    int i = blockIdx.x * blockDim.x + threadIdx.x;
    if (i < e) atomicAdd(&deg[dst[i]], 1.0f);
}

__global__ void deg_rsqrt_k(float* __restrict__ deg, int n) {
    int i = blockIdx.x * blockDim.x + threadIdx.x;
    if (i < n) deg[i] = rsqrtf(deg[i]);
}

// ---------------- dense layer: out[n,M] = act(in[n,K]) @ W[K,M] ----------------
// act = relu(x + bias_in) if RELU_IN else identity (bias/relu of the PREVIOUS
// layer are applied here, after aggregation, matching the reference).
template<int K, int M, bool RELU_IN>
__global__ __launch_bounds__(256) void gemm_k(const float* __restrict__ in,
                                              const float* __restrict__ bias_in,
                                              const float* __restrict__ W,
                                              float* __restrict__ out, int n) {
    constexpr int ROWS = 256 / M;           // rows per block: 16 / 4 / 2
    __shared__ float sW[K * M];
    __shared__ float sIn[ROWS][K];
    const int tid = threadIdx.x;
    for (int i = tid; i < K * M; i += 256) sW[i] = W[i];
    const int row0 = blockIdx.x * ROWS;
    for (int i = tid; i < ROWS * K; i += 256) {
        int r = i / K, k = i - r * K;
        int g = row0 + r;
        float v = 0.0f;
        if (g < n) {
            v = in[(long)g * K + k];
            if (RELU_IN) v = fmaxf(v + bias_in[k], 0.0f);
        }
        sIn[r][k] = v;
    }
    __syncthreads();
    const int r = tid / M, m = tid - r * M;
    const int g = row0 + r;
    if (g < n) {
        float acc = 0.0f;
#pragma unroll
        for (int k = 0; k < K; ++k) acc += sIn[r][k] * sW[k * M + m];
        out[(long)g * M + m] = acc;
    }
}

// ---------------- self-loop init: agg = hW * dinv^2 (plain store) ----------------
template<int M>
__global__ void selfloop_k(const float* __restrict__ hW, const float* __restrict__ dinv,
                           float* __restrict__ agg, int n) {
    long idx = (long)blockIdx.x * blockDim.x + threadIdx.x;
    long total = (long)n * M;
    if (idx < total) {
        int row = (int)(idx / M);
        float d = dinv[row];
        agg[idx] = hW[idx] * d * d;
    }
}

// ---------------- edge scatter: agg[dst] += hW[src] * dinv[src]*dinv[dst] ----------------
template<int M>
__global__ __launch_bounds__(256) void scatter_k(const int* __restrict__ src,
                                                 const int* __restrict__ dst,
                                                 const float* __restrict__ dinv,
                                                 const float* __restrict__ hW,
                                                 float* __restrict__ agg, int e) {
    constexpr int EPB = 256 / M;            // edges per block
    const int eid = blockIdx.x * EPB + threadIdx.x / M;
    const int c = threadIdx.x % M;
    if (eid < e) {
        const int s = src[eid];
        const int d = dst[eid];
        const float nrm = dinv[s] * dinv[d];
        atomicAdd(&agg[(long)d * M + c], hW[(long)s * M + c] * nrm);
    }
}

// ---------------- FC head: out[i] = relu(agg[i,:]+b3) . Wfc + bfc ----------------
__global__ __launch_bounds__(256) void fc_k(const float* __restrict__ agg,
                                            const float* __restrict__ b3,
                                            const float* __restrict__ Wfc,
                                            const float* __restrict__ bfc,
                                            float* __restrict__ out, int n) {
    const int wave = (blockIdx.x * blockDim.x + threadIdx.x) >> 6;
    const int lane = threadIdx.x & 63;
    if (wave >= n) return;
    const float* row = agg + (long)wave * 128;
    float v = fmaxf(row[lane] + b3[lane], 0.0f) * Wfc[lane]
            + fmaxf(row[lane + 64] + b3[lane + 64], 0.0f) * Wfc[lane + 64];
#pragma unroll
    for (int off = 32; off > 0; off >>= 1) v += __shfl_down(v, off, 64);
    if (lane == 0) out[wave] = v + bfc[0];
}

extern "C" void kernel_launch(void* const* d_in, const int* in_sizes, int n_in,
                              void* d_out, int out_size, void* d_ws, size_t ws_size,
                              hipStream_t stream) {
    const float* x    = (const float*)d_in[0];
    const int*   ei   = (const int*)d_in[1];       // [2,E]: src = ei, dst = ei+E
    const float* W1   = (const float*)d_in[2];
    const float* b1   = (const float*)d_in[3];
    const float* W2   = (const float*)d_in[4];
    const float* b2   = (const float*)d_in[5];
    const float* W3   = (const float*)d_in[6];
    const float* b3   = (const float*)d_in[7];
    const float* Wfc  = (const float*)d_in[8];
    const float* bfc  = (const float*)d_in[9];
    float* out = (float*)d_out;

    const int* src = ei;
    const int* dst = ei + NE;

    // workspace layout (floats): dinv[N] | hW[128N] | agg[128N]
    float* dinv = (float*)d_ws;
    float* hW   = dinv + NN;
    float* agg  = hW + (long)NN * 128;

    const int T = 256;

    // norm build
    deg_init_k<<<(NN + T - 1) / T, T, 0, stream>>>(dinv, NN);
    deg_count_k<<<(NE + T - 1) / T, T, 0, stream>>>(dst, dinv, NE);
    deg_rsqrt_k<<<(NN + T - 1) / T, T, 0, stream>>>(dinv, NN);

    // ---- layer 1: x[N,128] @ W1 -> 16 ----
    gemm_k<128, 16, false><<<(NN + 15) / 16, T, 0, stream>>>(x, nullptr, W1, hW, NN);
    selfloop_k<16><<<((long)NN * 16 + T - 1) / T, T, 0, stream>>>(hW, dinv, agg, NN);
    scatter_k<16><<<(NE + 15) / 16, T, 0, stream>>>(src, dst, dinv, hW, agg, NE);

    // ---- layer 2: relu(agg+b1)[N,16] @ W2 -> 64 ----
    gemm_k<16, 64, true><<<(NN + 3) / 4, T, 0, stream>>>(agg, b1, W2, hW, NN);
    selfloop_k<64><<<((long)NN * 64 + T - 1) / T, T, 0, stream>>>(hW, dinv, agg, NN);
    scatter_k<64><<<(NE + 3) / 4, T, 0, stream>>>(src, dst, dinv, hW, agg, NE);

    // ---- layer 3: relu(agg+b2)[N,64] @ W3 -> 128 ----
    gemm_k<64, 128, true><<<(NN + 1) / 2, T, 0, stream>>>(agg, b2, W3, hW, NN);
    selfloop_k<128><<<((long)NN * 128 + T - 1) / T, T, 0, stream>>>(hW, dinv, agg, NN);
    scatter_k<128><<<(NE + 1) / 2, T, 0, stream>>>(src, dst, dinv, hW, agg, NE);

    // ---- FC head ----
    fc_k<<<(NN * 64 + T - 1) / T, T, 0, stream>>>(agg, b3, Wfc, bfc, out, NN);
}

// Round 2
// 845.413 us; speedup vs baseline: 1.7753x; 1.7753x over previous
//
#include <hip/hip_runtime.h>

// GCN: N=100000, E=1600000, widths 128 -> 16 -> 64 -> 128 -> 1
// Algebraic reordering: S·(h@W) = (S·h)@W, so aggregate at the NARROW width:
//   L1: gemm(128->16) then scatter16 ; L2: scatter16 then gemm(16->64) ;
//   L3: scatter64 then fused gemm(64->128)+relu+Wfc head.
// Scatter channel-work 208 -> 96.

#define NN 100000
#define NE 1600000

// ---------------- degree / norm ----------------
__global__ void deg_init_k(float* __restrict__ deg, int n) {
    int i = blockIdx.x * blockDim.x + threadIdx.x;
    if (i < n) deg[i] = 1.0f;  // self loop
}

__global__ void deg_count_k(const int* __restrict__ dst, float* __restrict__ deg, int e) {
    int i = blockIdx.x * blockDim.x + threadIdx.x;
    if (i < e) atomicAdd(&deg[dst[i]], 1.0f);
}

__global__ void deg_rsqrt_k(float* __restrict__ deg, int n) {
    int i = blockIdx.x * blockDim.x + threadIdx.x;
    if (i < n) deg[i] = rsqrtf(deg[i]);
}

// ---------------- dense layer with fused epilogue ----------------
// acc = in[g,:K] @ W[K,M]; if BIAS_RELU: acc = relu(acc + bias[m]).
// Writes out_r[g,m] = acc and out_self[g,m] = acc * dinv[g]^2 (self-loop init
// for the subsequent aggregation).
template<int K, int M, bool BIAS_RELU>
__global__ __launch_bounds__(256) void gemm_k(const float* __restrict__ in,
                                              const float* __restrict__ bias,
                                              const float* __restrict__ W,
                                              const float* __restrict__ dinv,
                                              float* __restrict__ out_r,
                                              float* __restrict__ out_self, int n) {
    constexpr int ROWS = 256 / M;           // 16 for M=16, 4 for M=64
    __shared__ float sW[K * M];
    __shared__ float sIn[ROWS][K];
    const int tid = threadIdx.x;
    for (int i = tid; i < K * M; i += 256) sW[i] = W[i];
    const int row0 = blockIdx.x * ROWS;
    for (int i = tid; i < ROWS * K; i += 256) {
        int r = i / K, k = i - r * K;
        int g = row0 + r;
        sIn[r][k] = (g < n) ? in[(long)g * K + k] : 0.0f;
    }
    __syncthreads();
    const int r = tid / M, m = tid - r * M;
    const int g = row0 + r;
    if (g < n) {
        float acc = 0.0f;
#pragma unroll
        for (int k = 0; k < K; ++k) acc += sIn[r][k] * sW[k * M + m];
        if (BIAS_RELU) acc = fmaxf(acc + bias[m], 0.0f);
        const float d = dinv[g];
        out_r[(long)g * M + m] = acc;
        out_self[(long)g * M + m] = acc * d * d;
    }
}

// ---------------- prep: r = relu(agg + b); self = r * dinv^2 ----------------
template<int M>
__global__ void prep_k(const float* __restrict__ agg, const float* __restrict__ bias,
                       const float* __restrict__ dinv,
                       float* __restrict__ r_out, float* __restrict__ self_out, int n) {
    long idx = (long)blockIdx.x * blockDim.x + threadIdx.x;
    long total = (long)n * M;
    if (idx < total) {
        int row = (int)(idx / M);
        int c = (int)(idx - (long)row * M);
        float v = fmaxf(agg[idx] + bias[c], 0.0f);
        float d = dinv[row];
        r_out[idx] = v;
        self_out[idx] = v * d * d;
    }
}

// ---------------- edge scatter: agg[dst] += h[src] * dinv[src]*dinv[dst] ----------------
template<int M>
__global__ __launch_bounds__(256) void scatter_k(const int* __restrict__ src,
                                                 const int* __restrict__ dst,
                                                 const float* __restrict__ dinv,
                                                 const float* __restrict__ h,
                                                 float* __restrict__ agg, int e) {
    constexpr int EPB = 256 / M;            // edges per block
    const int eid = blockIdx.x * EPB + threadIdx.x / M;
    const int c = threadIdx.x % M;
    if (eid < e) {
        const int s = src[eid];
        const int d = dst[eid];
        const float nrm = dinv[s] * dinv[d];
        atomicAdd(&agg[(long)d * M + c], h[(long)s * M + c] * nrm);
    }
}

// ---------------- fused head: out[g] = relu(aggS2[g,:]@W3 + b3) . Wfc + bfc ----------------
// One wave per node (grid-stride). W3 staged in LDS as float2 pairs (m, m+64).
__global__ __launch_bounds__(256) void head_k(const float* __restrict__ aggS2,
                                              const float* __restrict__ W3,
                                              const float* __restrict__ b3,
                                              const float* __restrict__ Wfc,
                                              const float* __restrict__ bfc,
                                              float* __restrict__ out, int n) {
    __shared__ float2 sW[64 * 64];          // sW[k*64+m] = (W3[k][m], W3[k][m+64])
    const int tid = threadIdx.x;
    for (int i = tid; i < 64 * 64; i += 256) {
        int k = i >> 6, m = i & 63;
        sW[i] = make_float2(W3[k * 128 + m], W3[k * 128 + m + 64]);
    }
    __syncthreads();
    const int lane = tid & 63;
    const int waveInBlock = tid >> 6;
    const int nWaves = gridDim.x * 4;
    const float bm0 = b3[lane], bm1 = b3[lane + 64];
    const float w0 = Wfc[lane], w1 = Wfc[lane + 64];
    const float bb = bfc[0];
    for (int g = blockIdx.x * 4 + waveInBlock; g < n; g += nWaves) {
        const float rv = aggS2[(long)g * 64 + lane];   // lane k holds row[k]
        float acc0 = 0.0f, acc1 = 0.0f;
#pragma unroll
        for (int k = 0; k < 64; ++k) {
            const float x = __shfl(rv, k, 64);
            const float2 w = sW[k * 64 + lane];
            acc0 += x * w.x;
            acc1 += x * w.y;
        }
        float v = fmaxf(acc0 + bm0, 0.0f) * w0 + fmaxf(acc1 + bm1, 0.0f) * w1;
#pragma unroll
        for (int off = 32; off > 0; off >>= 1) v += __shfl_down(v, off, 64);
        if (lane == 0) out[g] = v + bb;
    }
}

extern "C" void kernel_launch(void* const* d_in, const int* in_sizes, int n_in,
                              void* d_out, int out_size, void* d_ws, size_t ws_size,
                              hipStream_t stream) {
    const float* x    = (const float*)d_in[0];
    const int*   ei   = (const int*)d_in[1];       // [2,E]: src = ei, dst = ei+E
    const float* W1   = (const float*)d_in[2];
    const float* b1   = (const float*)d_in[3];
    const float* W2   = (const float*)d_in[4];
    const float* b2   = (const float*)d_in[5];
    const float* W3   = (const float*)d_in[6];
    const float* b3   = (const float*)d_in[7];
    const float* Wfc  = (const float*)d_in[8];
    const float* bfc  = (const float*)d_in[9];
    float* out = (float*)d_out;

    const int* src = ei;
    const int* dst = ei + NE;

    // workspace (floats): dinv[N] | A[64N] | B[64N] | C[64N]  (~77 MB)
    float* dinv = (float*)d_ws;
    float* A = dinv + NN;
    float* B = A + (long)NN * 64;
    float* C = B + (long)NN * 64;

    const int T = 256;

    // norm build
    deg_init_k<<<(NN + T - 1) / T, T, 0, stream>>>(dinv, NN);
    deg_count_k<<<(NE + T - 1) / T, T, 0, stream>>>(dst, dinv, NE);
    deg_rsqrt_k<<<(NN + T - 1) / T, T, 0, stream>>>(dinv, NN);

    // ---- L1 GEMM: h1 = x@W1 -> A(16ch); self-init agg1 -> B(16ch) ----
    gemm_k<128, 16, false><<<(NN + 15) / 16, T, 0, stream>>>(x, nullptr, W1, dinv, A, B, NN);
    // agg1 = S.h1 : scatter into B
    scatter_k<16><<<(NE + 15) / 16, T, 0, stream>>>(src, dst, dinv, A, B, NE);

    // ---- r1 = relu(agg1 + b1) -> A(16ch); self-init aggS1 -> C(16ch) ----
    prep_k<16><<<((long)NN * 16 + T - 1) / T, T, 0, stream>>>(B, b1, dinv, A, C, NN);
    // aggS1 = S.r1 : scatter into C
    scatter_k<16><<<(NE + 15) / 16, T, 0, stream>>>(src, dst, dinv, A, C, NE);

    // ---- L2 GEMM: r2 = relu(aggS1@W2 + b2) -> A(64ch); self-init aggS2 -> B(64ch) ----
    gemm_k<16, 64, true><<<(NN + 3) / 4, T, 0, stream>>>(C, b2, W2, dinv, A, B, NN);
    // aggS2 = S.r2 : scatter into B
    scatter_k<64><<<(NE + 3) / 4, T, 0, stream>>>(src, dst, dinv, A, B, NE);

    // ---- fused L3 GEMM + head: out = relu(aggS2@W3 + b3).Wfc + bfc ----
    head_k<<<2048, T, 0, stream>>>(B, W3, b3, Wfc, bfc, out, NN);
}

// Round 3
// 627.420 us; speedup vs baseline: 2.3921x; 1.3474x over previous
//
#include <hip/hip_runtime.h>

// GCN: N=100000, E=1600000, widths 128 -> 16 -> 64 -> 128 -> 1
// Round 3: CSR pull-gather aggregation (no atomics in the hot path).
//   build dst-CSR once -> 3 gather-aggregations (16,16,64 ch), bias/relu fused.
// Pipeline:
//   A = x@W1                       (gemm 128->16)
//   B = relu(S.A + b1)             (gather16, fused epilogue)
//   C = S.B                        (gather16)
//   A = relu(C@W2 + b2)            (gemm 16->64, fused epilogue)
//   B = S.A                        (gather64)
//   out = relu(B@W3 + b3).Wfc+bfc  (head)

#define NN 100000
#define NE 1600000
#define NB ((NN + 255) / 256)   // 391 blocks for scans

// ---------------- degree / norm ----------------
__global__ void hist_k(const int* __restrict__ dst, int* __restrict__ ideg, int e) {
    int i = blockIdx.x * blockDim.x + threadIdx.x;
    if (i < e) atomicAdd(&ideg[dst[i]], 1);
}

__global__ void dinv_k(const int* __restrict__ ideg, float* __restrict__ dinv, int n) {
    int i = blockIdx.x * blockDim.x + threadIdx.x;
    if (i < n) dinv[i] = rsqrtf((float)ideg[i] + 1.0f);  // +1 self loop
}

// ---------------- exclusive scan (3 kernels) ----------------
__global__ void scan_reduce_k(const int* __restrict__ ideg, int* __restrict__ bsum, int n) {
    __shared__ int s[256];
    int i = blockIdx.x * 256 + threadIdx.x;
    s[threadIdx.x] = (i < n) ? ideg[i] : 0;
    __syncthreads();
    for (int off = 128; off > 0; off >>= 1) {
        if (threadIdx.x < off) s[threadIdx.x] += s[threadIdx.x + off];
        __syncthreads();
    }
    if (threadIdx.x == 0) bsum[blockIdx.x] = s[0];
}

__global__ __launch_bounds__(512) void scan_partials_k(const int* __restrict__ bsum,
                                                       int* __restrict__ bofs, int nb) {
    __shared__ int s[512];
    int t = threadIdx.x;
    int v = (t < nb) ? bsum[t] : 0;
    s[t] = v;
    __syncthreads();
    for (int off = 1; off < 512; off <<= 1) {
        int a = (t >= off) ? s[t - off] : 0;
        __syncthreads();
        s[t] += a;
        __syncthreads();
    }
    if (t < nb) bofs[t] = s[t] - v;  // exclusive
}

__global__ void scan_final_k(const int* __restrict__ ideg, const int* __restrict__ bofs,
                             int* __restrict__ rowptr, int* __restrict__ fill, int n, int e) {
    __shared__ int s[256];
    int i = blockIdx.x * 256 + threadIdx.x;
    int t = threadIdx.x;
    int v = (i < n) ? ideg[i] : 0;
    s[t] = v;
    __syncthreads();
    for (int off = 1; off < 256; off <<= 1) {
        int a = (t >= off) ? s[t - off] : 0;
        __syncthreads();
        s[t] += a;
        __syncthreads();
    }
    int excl = s[t] - v + bofs[blockIdx.x];
    if (i < n) { rowptr[i] = excl; fill[i] = excl; }
    if (i == 0) rowptr[n] = e;
}

// ---------------- CSR fill: csr_src[pos] = src, csr_nrm[pos] = dinv[src] ----------------
__global__ void fill_k(const int* __restrict__ src, const int* __restrict__ dst,
                       const float* __restrict__ dinv, int* __restrict__ fill,
                       int* __restrict__ csr_src, float* __restrict__ csr_nrm, int e) {
    int i = blockIdx.x * blockDim.x + threadIdx.x;
    if (i < e) {
        int d = dst[i], s = src[i];
        int pos = atomicAdd(&fill[d], 1);
        csr_src[pos] = s;
        csr_nrm[pos] = dinv[s];
    }
}

// ---------------- dense layer: out = act(in[n,K] @ W[K,M] + bias) ----------------
template<int K, int M, bool BIAS_RELU>
__global__ __launch_bounds__(256) void gemm_k(const float* __restrict__ in,
                                              const float* __restrict__ bias,
                                              const float* __restrict__ W,
                                              float* __restrict__ out, int n) {
    constexpr int ROWS = 256 / M;
    __shared__ float sW[K * M];
    __shared__ float sIn[ROWS][K];
    const int tid = threadIdx.x;
    for (int i = tid; i < K * M; i += 256) sW[i] = W[i];
    const int row0 = blockIdx.x * ROWS;
    for (int i = tid; i < ROWS * K; i += 256) {
        int r = i / K, k = i - r * K;
        int g = row0 + r;
        sIn[r][k] = (g < n) ? in[(long)g * K + k] : 0.0f;
    }
    __syncthreads();
    const int r = tid / M, m = tid - r * M;
    const int g = row0 + r;
    if (g < n) {
        float acc = 0.0f;
#pragma unroll
        for (int k = 0; k < K; ++k) acc += sIn[r][k] * sW[k * M + m];
        if (BIAS_RELU) acc = fmaxf(acc + bias[m], 0.0f);
        out[(long)g * M + m] = acc;
    }
}

// ---------------- pull-gather, 16 channels: one wave per node, 4 edges in flight ----------------
template<bool BIAS_RELU>
__global__ __launch_bounds__(256) void gather16_k(const int* __restrict__ rowptr,
                                                  const int* __restrict__ csr_src,
                                                  const float* __restrict__ csr_nrm,
                                                  const float* __restrict__ dinv,
                                                  const float* __restrict__ h,
                                                  const float* __restrict__ bias,
                                                  float* __restrict__ outp, int n) {
    const int g = (blockIdx.x * 256 + threadIdx.x) >> 6;
    if (g >= n) return;
    const int lane = threadIdx.x & 63;
    const int c = lane & 15, sub = lane >> 4;
    const float dg = dinv[g];
    const int beg = rowptr[g], end = rowptr[g + 1];
    float acc = (sub == 0) ? dg * dg * h[(long)g * 16 + c] : 0.0f;
    for (int j = beg + sub; j < end; j += 4) {
        const int s = csr_src[j];
        const float w = dg * csr_nrm[j];
        acc = fmaf(h[(long)s * 16 + c], w, acc);
    }
    acc += __shfl_down(acc, 32, 64);
    acc += __shfl_down(acc, 16, 64);
    if (lane < 16) {
        float v = acc;
        if (BIAS_RELU) v = fmaxf(v + bias[c], 0.0f);
        outp[(long)g * 16 + c] = v;
    }
}

// ---------------- pull-gather, 64 channels: one wave per node, lane = channel ----------------
__global__ __launch_bounds__(256) void gather64_k(const int* __restrict__ rowptr,
                                                  const int* __restrict__ csr_src,
                                                  const float* __restrict__ csr_nrm,
                                                  const float* __restrict__ dinv,
                                                  const float* __restrict__ h,
                                                  float* __restrict__ outp, int n) {
    const int g = (blockIdx.x * 256 + threadIdx.x) >> 6;
    if (g >= n) return;
    const int lane = threadIdx.x & 63;
    const float dg = dinv[g];
    const int beg = rowptr[g], end = rowptr[g + 1];
    float acc = dg * dg * h[(long)g * 64 + lane];
    int j = beg;
    for (; j + 2 <= end; j += 2) {
        const int s0 = csr_src[j], s1 = csr_src[j + 1];
        const float w0 = dg * csr_nrm[j], w1 = dg * csr_nrm[j + 1];
        const float v0 = h[(long)s0 * 64 + lane];
        const float v1 = h[(long)s1 * 64 + lane];
        acc = fmaf(v0, w0, acc);
        acc = fmaf(v1, w1, acc);
    }
    if (j < end) {
        const int s0 = csr_src[j];
        acc = fmaf(h[(long)s0 * 64 + lane], dg * csr_nrm[j], acc);
    }
    outp[(long)g * 64 + lane] = acc;
}

// ---------------- fused head: out[g] = relu(aggS2[g,:]@W3 + b3) . Wfc + bfc ----------------
__global__ __launch_bounds__(256) void head_k(const float* __restrict__ aggS2,
                                              const float* __restrict__ W3,
                                              const float* __restrict__ b3,
                                              const float* __restrict__ Wfc,
                                              const float* __restrict__ bfc,
                                              float* __restrict__ out, int n) {
    __shared__ float2 sW[64 * 64];          // sW[k*64+m] = (W3[k][m], W3[k][m+64])
    const int tid = threadIdx.x;
    for (int i = tid; i < 64 * 64; i += 256) {
        int k = i >> 6, m = i & 63;
        sW[i] = make_float2(W3[k * 128 + m], W3[k * 128 + m + 64]);
    }
    __syncthreads();
    const int lane = tid & 63;
    const int waveInBlock = tid >> 6;
    const int nWaves = gridDim.x * 4;
    const float bm0 = b3[lane], bm1 = b3[lane + 64];
    const float w0 = Wfc[lane], w1 = Wfc[lane + 64];
    const float bb = bfc[0];
    for (int g = blockIdx.x * 4 + waveInBlock; g < n; g += nWaves) {
        const float rv = aggS2[(long)g * 64 + lane];
        float acc0 = 0.0f, acc1 = 0.0f;
#pragma unroll
        for (int k = 0; k < 64; ++k) {
            const float x = __shfl(rv, k, 64);
            const float2 w = sW[k * 64 + lane];
            acc0 += x * w.x;
            acc1 += x * w.y;
        }
        float v = fmaxf(acc0 + bm0, 0.0f) * w0 + fmaxf(acc1 + bm1, 0.0f) * w1;
#pragma unroll
        for (int off = 32; off > 0; off >>= 1) v += __shfl_down(v, off, 64);
        if (lane == 0) out[g] = v + bb;
    }
}

extern "C" void kernel_launch(void* const* d_in, const int* in_sizes, int n_in,
                              void* d_out, int out_size, void* d_ws, size_t ws_size,
                              hipStream_t stream) {
    const float* x    = (const float*)d_in[0];
    const int*   ei   = (const int*)d_in[1];       // [2,E]: src = ei, dst = ei+E
    const float* W1   = (const float*)d_in[2];
    const float* b1   = (const float*)d_in[3];
    const float* W2   = (const float*)d_in[4];
    const float* b2   = (const float*)d_in[5];
    const float* W3   = (const float*)d_in[6];
    const float* b3   = (const float*)d_in[7];
    const float* Wfc  = (const float*)d_in[8];
    const float* bfc  = (const float*)d_in[9];
    float* out = (float*)d_out;

    const int* src = ei;
    const int* dst = ei + NE;

    // workspace layout (all 4-byte elems):
    // dinv[N] | ideg[N] | rowptr[N+8] | fill[N] | bsum[512] | bofs[512]
    // | csr_src[E] | csr_nrm[E] | A[64N] | B[64N] | C[64N]   (~91 MB)
    float* dinv    = (float*)d_ws;
    int*   ideg    = (int*)(dinv + NN);
    int*   rowptr  = ideg + NN;
    int*   fill    = rowptr + NN + 8;
    int*   bsum    = fill + NN;
    int*   bofs    = bsum + 512;
    int*   csr_src = bofs + 512;
    float* csr_nrm = (float*)(csr_src + NE);
    float* A       = csr_nrm + NE;
    float* B       = A + (long)NN * 64;
    float* C       = B + (long)NN * 64;

    const int T = 256;

    // ---- CSR + norm build ----
    hipMemsetAsync(ideg, 0, NN * sizeof(int), stream);
    hist_k<<<(NE + T - 1) / T, T, 0, stream>>>(dst, ideg, NE);
    dinv_k<<<(NN + T - 1) / T, T, 0, stream>>>(ideg, dinv, NN);
    scan_reduce_k<<<NB, T, 0, stream>>>(ideg, bsum, NN);
    scan_partials_k<<<1, 512, 0, stream>>>(bsum, bofs, NB);
    scan_final_k<<<NB, T, 0, stream>>>(ideg, bofs, rowptr, fill, NN, NE);
    fill_k<<<(NE + T - 1) / T, T, 0, stream>>>(src, dst, dinv, fill, csr_src, csr_nrm, NE);

    // ---- L1 GEMM: A = x@W1 (128->16) ----
    gemm_k<128, 16, false><<<(NN + 15) / 16, T, 0, stream>>>(x, nullptr, W1, A, NN);
    // ---- B = relu(S.A + b1) ----
    gather16_k<true><<<(NN + 3) / 4, T, 0, stream>>>(rowptr, csr_src, csr_nrm, dinv, A, b1, B, NN);
    // ---- C = S.B ----
    gather16_k<false><<<(NN + 3) / 4, T, 0, stream>>>(rowptr, csr_src, csr_nrm, dinv, B, nullptr, C, NN);
    // ---- A = relu(C@W2 + b2) (16->64) ----
    gemm_k<16, 64, true><<<(NN + 3) / 4, T, 0, stream>>>(C, b2, W2, A, NN);
    // ---- B = S.A ----
    gather64_k<<<(NN + 3) / 4, T, 0, stream>>>(rowptr, csr_src, csr_nrm, dinv, A, B, NN);
    // ---- head: out = relu(B@W3 + b3).Wfc + bfc ----
    head_k<<<2048, T, 0, stream>>>(B, W3, b3, Wfc, bfc, out, NN);
}

// Round 4
// 559.256 us; speedup vs baseline: 2.6837x; 1.1219x over previous
//
#include <hip/hip_runtime.h>

// GCN: N=100000, E=1600000, widths 128 -> 16 -> 64 -> 128 -> 1
// Round 4: (a) CSR payload fused to one int2 (src, dinv[src]) -> one 8B
// scattered store per edge (half the dirty lines of round 3);
// (b) multi-edge-in-flight float4 gathers (16 edges in flight for 16ch,
// 4 for 64ch) to attack gather latency; (c) float4 GEMM staging.

#define NN 100000
#define NE 1600000
#define NB ((NN + 255) / 256)   // 391 blocks for scans

// ---------------- degree ----------------
__global__ void hist_k(const int* __restrict__ dst, int* __restrict__ ideg, int e) {
    int i = blockIdx.x * blockDim.x + threadIdx.x;
    if (i < e) atomicAdd(&ideg[dst[i]], 1);
}

__global__ void dinv_k(const int* __restrict__ ideg, float* __restrict__ dinv, int n) {
    int i = blockIdx.x * blockDim.x + threadIdx.x;
    if (i < n) dinv[i] = rsqrtf((float)ideg[i] + 1.0f);  // +1 self loop
}

// ---------------- exclusive scan (3 kernels) ----------------
__global__ void scan_reduce_k(const int* __restrict__ ideg, int* __restrict__ bsum, int n) {
    __shared__ int s[256];
    int i = blockIdx.x * 256 + threadIdx.x;
    s[threadIdx.x] = (i < n) ? ideg[i] : 0;
    __syncthreads();
    for (int off = 128; off > 0; off >>= 1) {
        if (threadIdx.x < off) s[threadIdx.x] += s[threadIdx.x + off];
        __syncthreads();
    }
    if (threadIdx.x == 0) bsum[blockIdx.x] = s[0];
}

__global__ __launch_bounds__(512) void scan_partials_k(const int* __restrict__ bsum,
                                                       int* __restrict__ bofs, int nb) {
    __shared__ int s[512];
    int t = threadIdx.x;
    int v = (t < nb) ? bsum[t] : 0;
    s[t] = v;
    __syncthreads();
    for (int off = 1; off < 512; off <<= 1) {
        int a = (t >= off) ? s[t - off] : 0;
        __syncthreads();
        s[t] += a;
        __syncthreads();
    }
    if (t < nb) bofs[t] = s[t] - v;  // exclusive
}

__global__ void scan_final_k(const int* __restrict__ ideg, const int* __restrict__ bofs,
                             int* __restrict__ rowptr, int* __restrict__ fill, int n, int e) {
    __shared__ int s[256];
    int i = blockIdx.x * 256 + threadIdx.x;
    int t = threadIdx.x;
    int v = (i < n) ? ideg[i] : 0;
    s[t] = v;
    __syncthreads();
    for (int off = 1; off < 256; off <<= 1) {
        int a = (t >= off) ? s[t - off] : 0;
        __syncthreads();
        s[t] += a;
        __syncthreads();
    }
    int excl = s[t] - v + bofs[blockIdx.x];
    if (i < n) { rowptr[i] = excl; fill[i] = excl; }
    if (i == 0) rowptr[n] = e;
}

// ---------------- CSR fill: csr[pos] = (src, dinv[src]) — one 8B store ----------------
__global__ void fill_k(const int* __restrict__ src, const int* __restrict__ dst,
                       const float* __restrict__ dinv, int* __restrict__ fill,
                       int2* __restrict__ csr, int e) {
    int i = blockIdx.x * blockDim.x + threadIdx.x;
    if (i < e) {
        int d = dst[i], s = src[i];
        int pos = atomicAdd(&fill[d], 1);
        csr[pos] = make_int2(s, __float_as_int(dinv[s]));
    }
}

// ---------------- dense layer: out = act(in[n,K] @ W[K,M] + bias) ----------------
template<int K, int M, bool BIAS_RELU>
__global__ __launch_bounds__(256) void gemm_k(const float* __restrict__ in,
                                              const float* __restrict__ bias,
                                              const float* __restrict__ W,
                                              float* __restrict__ out, int n) {
    constexpr int ROWS = 256 / M;
    constexpr int KV = K / 4;
    __shared__ float sW[K * M];
    __shared__ float sIn[ROWS][K + 4];      // +4 pad: kill 4-way bank conflict
    const int tid = threadIdx.x;
    for (int i = tid; i < K * M; i += 256) sW[i] = W[i];
    const int row0 = blockIdx.x * ROWS;
    const float4* in4 = (const float4*)in;
    for (int i = tid; i < ROWS * KV; i += 256) {
        int r = i / KV, kv = i - r * KV;
        int g = row0 + r;
        float4 v = make_float4(0.f, 0.f, 0.f, 0.f);
        if (g < n) v = in4[(long)g * KV + kv];
        ((float4*)&sIn[r][0])[kv] = v;
    }
    __syncthreads();
    const int r = tid / M, m = tid - r * M;
    const int g = row0 + r;
    if (g < n) {
        float acc = 0.0f;
#pragma unroll
        for (int k = 0; k < K; ++k) acc += sIn[r][k] * sW[k * M + m];
        if (BIAS_RELU) acc = fmaxf(acc + bias[m], 0.0f);
        out[(long)g * M + m] = acc;
    }
}

// ---------------- pull-gather, 16 ch: wave = 16 edge-subs x 4 float4-lanes ----------------
template<bool BIAS_RELU>
__global__ __launch_bounds__(256) void gather16_k(const int* __restrict__ rowptr,
                                                  const int2* __restrict__ csr,
                                                  const float* __restrict__ dinv,
                                                  const float* __restrict__ h,
                                                  const float* __restrict__ bias,
                                                  float* __restrict__ outp, int n) {
    const int g = (blockIdx.x * 256 + threadIdx.x) >> 6;
    if (g >= n) return;
    const int lane = threadIdx.x & 63;
    const int q = lane & 3;                 // float4 index within 16-ch row
    const int sub = lane >> 2;              // edge subgroup 0..15
    const float dg = dinv[g];
    const int beg = rowptr[g], end = rowptr[g + 1];
    const float4* h4 = (const float4*)h;
    float4 acc;
    {   // self-loop term: h[g] * dg (outer dg applied at the end)
        float4 v = h4[(long)g * 4 + q];
        float w = (sub == 0) ? dg : 0.0f;
        acc = make_float4(v.x * w, v.y * w, v.z * w, v.w * w);
    }
    for (int j0 = beg; j0 < end; j0 += 16) {
        int idx = j0 + sub;
        int s = g; float w = 0.0f;
        if (idx < end) {
            int2 p = csr[idx];
            s = p.x; w = __int_as_float(p.y);
        }
        float4 v = h4[(long)s * 4 + q];
        acc.x = fmaf(v.x, w, acc.x);
        acc.y = fmaf(v.y, w, acc.y);
        acc.z = fmaf(v.z, w, acc.z);
        acc.w = fmaf(v.w, w, acc.w);
    }
#pragma unroll
    for (int m = 4; m <= 32; m <<= 1) {
        acc.x += __shfl_xor(acc.x, m, 64);
        acc.y += __shfl_xor(acc.y, m, 64);
        acc.z += __shfl_xor(acc.z, m, 64);
        acc.w += __shfl_xor(acc.w, m, 64);
    }
    if (sub == 0) {
        float4 v = make_float4(acc.x * dg, acc.y * dg, acc.z * dg, acc.w * dg);
        if (BIAS_RELU) {
            const float4 b = ((const float4*)bias)[q];
            v.x = fmaxf(v.x + b.x, 0.0f);
            v.y = fmaxf(v.y + b.y, 0.0f);
            v.z = fmaxf(v.z + b.z, 0.0f);
            v.w = fmaxf(v.w + b.w, 0.0f);
        }
        ((float4*)outp)[(long)g * 4 + q] = v;
    }
}

// ---------------- pull-gather, 64 ch: wave = 4 edge-subs x 16 float4-lanes ----------------
__global__ __launch_bounds__(256) void gather64_k(const int* __restrict__ rowptr,
                                                  const int2* __restrict__ csr,
                                                  const float* __restrict__ dinv,
                                                  const float* __restrict__ h,
                                                  float* __restrict__ outp, int n) {
    const int g = (blockIdx.x * 256 + threadIdx.x) >> 6;
    if (g >= n) return;
    const int lane = threadIdx.x & 63;
    const int q = lane & 15;                // float4 index within 64-ch row
    const int sub = lane >> 4;              // edge subgroup 0..3
    const float dg = dinv[g];
    const int beg = rowptr[g], end = rowptr[g + 1];
    const float4* h4 = (const float4*)h;
    float4 acc;
    {
        float4 v = h4[(long)g * 16 + q];
        float w = (sub == 0) ? dg : 0.0f;
        acc = make_float4(v.x * w, v.y * w, v.z * w, v.w * w);
    }
    for (int j0 = beg; j0 < end; j0 += 4) {
        int idx = j0 + sub;
        int s = g; float w = 0.0f;
        if (idx < end) {
            int2 p = csr[idx];
            s = p.x; w = __int_as_float(p.y);
        }
        float4 v = h4[(long)s * 16 + q];
        acc.x = fmaf(v.x, w, acc.x);
        acc.y = fmaf(v.y, w, acc.y);
        acc.z = fmaf(v.z, w, acc.z);
        acc.w = fmaf(v.w, w, acc.w);
    }
#pragma unroll
    for (int m = 16; m <= 32; m <<= 1) {
        acc.x += __shfl_xor(acc.x, m, 64);
        acc.y += __shfl_xor(acc.y, m, 64);
        acc.z += __shfl_xor(acc.z, m, 64);
        acc.w += __shfl_xor(acc.w, m, 64);
    }
    if (sub == 0) {
        float4 v = make_float4(acc.x * dg, acc.y * dg, acc.z * dg, acc.w * dg);
        ((float4*)outp)[(long)g * 16 + q] = v;
    }
}

// ---------------- fused head: out[g] = relu(aggS2[g,:]@W3 + b3) . Wfc + bfc ----------------
__global__ __launch_bounds__(256) void head_k(const float* __restrict__ aggS2,
                                              const float* __restrict__ W3,
                                              const float* __restrict__ b3,
                                              const float* __restrict__ Wfc,
                                              const float* __restrict__ bfc,
                                              float* __restrict__ out, int n) {
    __shared__ float2 sW[64 * 64];          // sW[k*64+m] = (W3[k][m], W3[k][m+64])
    const int tid = threadIdx.x;
    for (int i = tid; i < 64 * 64; i += 256) {
        int k = i >> 6, m = i & 63;
        sW[i] = make_float2(W3[k * 128 + m], W3[k * 128 + m + 64]);
    }
    __syncthreads();
    const int lane = tid & 63;
    const int waveInBlock = tid >> 6;
    const int nWaves = gridDim.x * 4;
    const float bm0 = b3[lane], bm1 = b3[lane + 64];
    const float w0 = Wfc[lane], w1 = Wfc[lane + 64];
    const float bb = bfc[0];
    for (int g = blockIdx.x * 4 + waveInBlock; g < n; g += nWaves) {
        const float rv = aggS2[(long)g * 64 + lane];
        float acc0 = 0.0f, acc1 = 0.0f;
#pragma unroll
        for (int k = 0; k < 64; ++k) {
            const float x = __shfl(rv, k, 64);
            const float2 w = sW[k * 64 + lane];
            acc0 += x * w.x;
            acc1 += x * w.y;
        }
        float v = fmaxf(acc0 + bm0, 0.0f) * w0 + fmaxf(acc1 + bm1, 0.0f) * w1;
#pragma unroll
        for (int off = 32; off > 0; off >>= 1) v += __shfl_down(v, off, 64);
        if (lane == 0) out[g] = v + bb;
    }
}

extern "C" void kernel_launch(void* const* d_in, const int* in_sizes, int n_in,
                              void* d_out, int out_size, void* d_ws, size_t ws_size,
                              hipStream_t stream) {
    const float* x    = (const float*)d_in[0];
    const int*   ei   = (const int*)d_in[1];       // [2,E]: src = ei, dst = ei+E
    const float* W1   = (const float*)d_in[2];
    const float* b1   = (const float*)d_in[3];
    const float* W2   = (const float*)d_in[4];
    const float* b2   = (const float*)d_in[5];
    const float* W3   = (const float*)d_in[6];
    const float* b3   = (const float*)d_in[7];
    const float* Wfc  = (const float*)d_in[8];
    const float* bfc  = (const float*)d_in[9];
    float* out = (float*)d_out;

    const int* src = ei;
    const int* dst = ei + NE;

    // workspace layout (4-byte elems; all arena offsets 16B-aligned):
    // dinv[N] | ideg[N] | rowptr[N+8] | fill[N] | bsum[512] | bofs[512]
    // | csr[2E] | A[64N] | B[64N] | C[64N]   (~91 MB)
    float* dinv    = (float*)d_ws;
    int*   ideg    = (int*)(dinv + NN);
    int*   rowptr  = ideg + NN;
    int*   fill    = rowptr + NN + 8;
    int*   bsum    = fill + NN;
    int*   bofs    = bsum + 512;
    int2*  csr     = (int2*)(bofs + 512);
    float* A       = (float*)(csr + NE);
    float* B       = A + (long)NN * 64;
    float* C       = B + (long)NN * 64;

    const int T = 256;

    // ---- CSR + norm build ----
    hipMemsetAsync(ideg, 0, NN * sizeof(int), stream);
    hist_k<<<(NE + T - 1) / T, T, 0, stream>>>(dst, ideg, NE);
    dinv_k<<<(NN + T - 1) / T, T, 0, stream>>>(ideg, dinv, NN);
    scan_reduce_k<<<NB, T, 0, stream>>>(ideg, bsum, NN);
    scan_partials_k<<<1, 512, 0, stream>>>(bsum, bofs, NB);
    scan_final_k<<<NB, T, 0, stream>>>(ideg, bofs, rowptr, fill, NN, NE);
    fill_k<<<(NE + T - 1) / T, T, 0, stream>>>(src, dst, dinv, fill, csr, NE);

    // ---- L1 GEMM: A = x@W1 (128->16) ----
    gemm_k<128, 16, false><<<(NN + 15) / 16, T, 0, stream>>>(x, nullptr, W1, A, NN);
    // ---- B = relu(S.A + b1) ----
    gather16_k<true><<<(NN + 3) / 4, T, 0, stream>>>(rowptr, csr, dinv, A, b1, B, NN);
    // ---- C = S.B ----
    gather16_k<false><<<(NN + 3) / 4, T, 0, stream>>>(rowptr, csr, dinv, B, nullptr, C, NN);
    // ---- A = relu(C@W2 + b2) (16->64) ----
    gemm_k<16, 64, true><<<(NN + 3) / 4, T, 0, stream>>>(C, b2, W2, A, NN);
    // ---- B = S.A ----
    gather64_k<<<(NN + 3) / 4, T, 0, stream>>>(rowptr, csr, dinv, A, B, NN);
    // ---- head: out = relu(B@W3 + b3).Wfc + bfc ----
    head_k<<<2048, T, 0, stream>>>(B, W3, b3, Wfc, bfc, out, NN);
}

// Round 5
// 491.803 us; speedup vs baseline: 3.0517x; 1.1372x over previous
//
#include <hip/hip_runtime.h>

// GCN: N=100000, E=1600000, widths 128 -> 16 -> 64 -> 128 -> 1
// Round 5: (a) atomic-free CSR fill: rank[i] = atomicAdd(ideg[dst],1) in the
// histogram pass, then pos = rowptr[dst] + rank (plain scattered 4B store);
// (b) weight-free gathers: producers write dinv-scaled features, so
// S.X = dg*(Xs[g] + sum Xs[src]) and csr payload is just src (4B/edge).

#define NN 100000
#define NE 1600000
#define NB ((NN + 255) / 256)   // 391 blocks for scans

// ---------------- histogram + rank ----------------
__global__ void hist_rank_k(const int* __restrict__ dst, int* __restrict__ ideg,
                            int* __restrict__ rank, int e) {
    int i = blockIdx.x * blockDim.x + threadIdx.x;
    if (i < e) rank[i] = atomicAdd(&ideg[dst[i]], 1);
}

__global__ void dinv_k(const int* __restrict__ ideg, float* __restrict__ dinv, int n) {
    int i = blockIdx.x * blockDim.x + threadIdx.x;
    if (i < n) dinv[i] = rsqrtf((float)ideg[i] + 1.0f);  // +1 self loop
}

// ---------------- exclusive scan (3 kernels) ----------------
__global__ void scan_reduce_k(const int* __restrict__ ideg, int* __restrict__ bsum, int n) {
    __shared__ int s[256];
    int i = blockIdx.x * 256 + threadIdx.x;
    s[threadIdx.x] = (i < n) ? ideg[i] : 0;
    __syncthreads();
    for (int off = 128; off > 0; off >>= 1) {
        if (threadIdx.x < off) s[threadIdx.x] += s[threadIdx.x + off];
        __syncthreads();
    }
    if (threadIdx.x == 0) bsum[blockIdx.x] = s[0];
}

__global__ __launch_bounds__(512) void scan_partials_k(const int* __restrict__ bsum,
                                                       int* __restrict__ bofs, int nb) {
    __shared__ int s[512];
    int t = threadIdx.x;
    int v = (t < nb) ? bsum[t] : 0;
    s[t] = v;
    __syncthreads();
    for (int off = 1; off < 512; off <<= 1) {
        int a = (t >= off) ? s[t - off] : 0;
        __syncthreads();
        s[t] += a;
        __syncthreads();
    }
    if (t < nb) bofs[t] = s[t] - v;  // exclusive
}

__global__ void scan_final_k(const int* __restrict__ ideg, const int* __restrict__ bofs,
                             int* __restrict__ rowptr, int n, int e) {
    __shared__ int s[256];
    int i = blockIdx.x * 256 + threadIdx.x;
    int t = threadIdx.x;
    int v = (i < n) ? ideg[i] : 0;
    s[t] = v;
    __syncthreads();
    for (int off = 1; off < 256; off <<= 1) {
        int a = (t >= off) ? s[t - off] : 0;
        __syncthreads();
        s[t] += a;
        __syncthreads();
    }
    int excl = s[t] - v + bofs[blockIdx.x];
    if (i < n) rowptr[i] = excl;
    if (i == 0) rowptr[n] = e;
}

// ---------------- CSR fill: no atomics ----------------
__global__ void fill_k(const int* __restrict__ src, const int* __restrict__ dst,
                       const int* __restrict__ rank, const int* __restrict__ rowptr,
                       int* __restrict__ csr_src, int e) {
    int i = blockIdx.x * blockDim.x + threadIdx.x;
    if (i < e) csr_src[rowptr[dst[i]] + rank[i]] = src[i];
}

// ---------------- dense layer: out = scale? dinv[g]*act(in@W + b) ----------------
template<int K, int M, bool BIAS_RELU, bool SCALE>
__global__ __launch_bounds__(256) void gemm_k(const float* __restrict__ in,
                                              const float* __restrict__ bias,
                                              const float* __restrict__ W,
                                              const float* __restrict__ dinv,
                                              float* __restrict__ out, int n) {
    constexpr int ROWS = 256 / M;
    constexpr int KV = K / 4;
    __shared__ float sW[K * M];
    __shared__ float sIn[ROWS][K + 4];      // +4 pad: kill 4-way bank conflict
    const int tid = threadIdx.x;
    for (int i = tid; i < K * M; i += 256) sW[i] = W[i];
    const int row0 = blockIdx.x * ROWS;
    const float4* in4 = (const float4*)in;
    for (int i = tid; i < ROWS * KV; i += 256) {
        int r = i / KV, kv = i - r * KV;
        int g = row0 + r;
        float4 v = make_float4(0.f, 0.f, 0.f, 0.f);
        if (g < n) v = in4[(long)g * KV + kv];
        ((float4*)&sIn[r][0])[kv] = v;
    }
    __syncthreads();
    const int r = tid / M, m = tid - r * M;
    const int g = row0 + r;
    if (g < n) {
        float acc = 0.0f;
#pragma unroll
        for (int k = 0; k < K; ++k) acc += sIn[r][k] * sW[k * M + m];
        if (BIAS_RELU) acc = fmaxf(acc + bias[m], 0.0f);
        if (SCALE) acc *= dinv[g];
        out[(long)g * M + m] = acc;
    }
}

// ---------------- pull-gather, 16 ch (weight-free) ----------------
// in = pre-scaled hs; out = [relu](dg*(hs[g]+sum hs[src]) + b) [* dg if OUT_SCALE]
template<bool BIAS_RELU, bool OUT_SCALE>
__global__ __launch_bounds__(256) void gather16_k(const int* __restrict__ rowptr,
                                                  const int* __restrict__ csr_src,
                                                  const float* __restrict__ dinv,
                                                  const float* __restrict__ hs,
                                                  const float* __restrict__ bias,
                                                  float* __restrict__ outp, int n) {
    const int g = (blockIdx.x * 256 + threadIdx.x) >> 6;
    if (g >= n) return;
    const int lane = threadIdx.x & 63;
    const int q = lane & 3;                 // float4 index within 16-ch row
    const int sub = lane >> 2;              // edge subgroup 0..15
    const float dg = dinv[g];
    const int beg = rowptr[g], end = rowptr[g + 1];
    const float4* h4 = (const float4*)hs;
    float4 acc = make_float4(0.f, 0.f, 0.f, 0.f);
    if (sub == 0) acc = h4[(long)g * 4 + q];  // self term
    for (int j0 = beg; j0 < end; j0 += 16) {
        int idx = j0 + sub;
        if (idx < end) {
            const int s = csr_src[idx];
            const float4 v = h4[(long)s * 4 + q];
            acc.x += v.x; acc.y += v.y; acc.z += v.z; acc.w += v.w;
        }
    }
#pragma unroll
    for (int m = 4; m <= 32; m <<= 1) {
        acc.x += __shfl_xor(acc.x, m, 64);
        acc.y += __shfl_xor(acc.y, m, 64);
        acc.z += __shfl_xor(acc.z, m, 64);
        acc.w += __shfl_xor(acc.w, m, 64);
    }
    if (sub == 0) {
        float4 v = make_float4(acc.x * dg, acc.y * dg, acc.z * dg, acc.w * dg);
        if (BIAS_RELU) {
            const float4 b = ((const float4*)bias)[q];
            v.x = fmaxf(v.x + b.x, 0.0f);
            v.y = fmaxf(v.y + b.y, 0.0f);
            v.z = fmaxf(v.z + b.z, 0.0f);
            v.w = fmaxf(v.w + b.w, 0.0f);
        }
        if (OUT_SCALE) { v.x *= dg; v.y *= dg; v.z *= dg; v.w *= dg; }
        ((float4*)outp)[(long)g * 4 + q] = v;
    }
}

// ---------------- pull-gather, 64 ch (weight-free, 2x unrolled) ----------------
__global__ __launch_bounds__(256) void gather64_k(const int* __restrict__ rowptr,
                                                  const int* __restrict__ csr_src,
                                                  const float* __restrict__ dinv,
                                                  const float* __restrict__ hs,
                                                  float* __restrict__ outp, int n) {
    const int g = (blockIdx.x * 256 + threadIdx.x) >> 6;
    if (g >= n) return;
    const int lane = threadIdx.x & 63;
    const int q = lane & 15;                // float4 index within 64-ch row
    const int sub = lane >> 4;              // edge subgroup 0..3
    const float dg = dinv[g];
    const int beg = rowptr[g], end = rowptr[g + 1];
    const float4* h4 = (const float4*)hs;
    float4 acc = make_float4(0.f, 0.f, 0.f, 0.f);
    if (sub == 0) acc = h4[(long)g * 16 + q];  // self term
    int j0 = beg;
    for (; j0 + 8 <= end; j0 += 8) {
        const int s0 = csr_src[j0 + sub];
        const int s1 = csr_src[j0 + 4 + sub];
        const float4 v0 = h4[(long)s0 * 16 + q];
        const float4 v1 = h4[(long)s1 * 16 + q];
        acc.x += v0.x + v1.x; acc.y += v0.y + v1.y;
        acc.z += v0.z + v1.z; acc.w += v0.w + v1.w;
    }
    for (; j0 < end; j0 += 4) {
        int idx = j0 + sub;
        if (idx < end) {
            const int s = csr_src[idx];
            const float4 v = h4[(long)s * 16 + q];
            acc.x += v.x; acc.y += v.y; acc.z += v.z; acc.w += v.w;
        }
    }
#pragma unroll
    for (int m = 16; m <= 32; m <<= 1) {
        acc.x += __shfl_xor(acc.x, m, 64);
        acc.y += __shfl_xor(acc.y, m, 64);
        acc.z += __shfl_xor(acc.z, m, 64);
        acc.w += __shfl_xor(acc.w, m, 64);
    }
    if (sub == 0) {
        ((float4*)outp)[(long)g * 16 + q] =
            make_float4(acc.x * dg, acc.y * dg, acc.z * dg, acc.w * dg);
    }
}

// ---------------- fused head: out[g] = relu(aggS2[g,:]@W3 + b3) . Wfc + bfc ----------------
__global__ __launch_bounds__(256) void head_k(const float* __restrict__ aggS2,
                                              const float* __restrict__ W3,
                                              const float* __restrict__ b3,
                                              const float* __restrict__ Wfc,
                                              const float* __restrict__ bfc,
                                              float* __restrict__ out, int n) {
    __shared__ float2 sW[64 * 64];          // sW[k*64+m] = (W3[k][m], W3[k][m+64])
    const int tid = threadIdx.x;
    for (int i = tid; i < 64 * 64; i += 256) {
        int k = i >> 6, m = i & 63;
        sW[i] = make_float2(W3[k * 128 + m], W3[k * 128 + m + 64]);
    }
    __syncthreads();
    const int lane = tid & 63;
    const int waveInBlock = tid >> 6;
    const int nWaves = gridDim.x * 4;
    const float bm0 = b3[lane], bm1 = b3[lane + 64];
    const float w0 = Wfc[lane], w1 = Wfc[lane + 64];
    const float bb = bfc[0];
    for (int g = blockIdx.x * 4 + waveInBlock; g < n; g += nWaves) {
        const float rv = aggS2[(long)g * 64 + lane];
        float acc0 = 0.0f, acc1 = 0.0f;
#pragma unroll
        for (int k = 0; k < 64; ++k) {
            const float x = __shfl(rv, k, 64);
            const float2 w = sW[k * 64 + lane];
            acc0 += x * w.x;
            acc1 += x * w.y;
        }
        float v = fmaxf(acc0 + bm0, 0.0f) * w0 + fmaxf(acc1 + bm1, 0.0f) * w1;
#pragma unroll
        for (int off = 32; off > 0; off >>= 1) v += __shfl_down(v, off, 64);
        if (lane == 0) out[g] = v + bb;
    }
}

extern "C" void kernel_launch(void* const* d_in, const int* in_sizes, int n_in,
                              void* d_out, int out_size, void* d_ws, size_t ws_size,
                              hipStream_t stream) {
    const float* x    = (const float*)d_in[0];
    const int*   ei   = (const int*)d_in[1];       // [2,E]: src = ei, dst = ei+E
    const float* W1   = (const float*)d_in[2];
    const float* b1   = (const float*)d_in[3];
    const float* W2   = (const float*)d_in[4];
    const float* b2   = (const float*)d_in[5];
    const float* W3   = (const float*)d_in[6];
    const float* b3   = (const float*)d_in[7];
    const float* Wfc  = (const float*)d_in[8];
    const float* bfc  = (const float*)d_in[9];
    float* out = (float*)d_out;

    const int* src = ei;
    const int* dst = ei + NE;

    // workspace layout (4-byte elems; A offset is 16B-aligned):
    // dinv[N] | ideg[N] | rowptr[N+8] | bsum[512] | bofs[512] | rank[E]
    // | csr_src[E] | A[64N] | B[64N] | C[64N]   (~91 MB)
    float* dinv    = (float*)d_ws;
    int*   ideg    = (int*)(dinv + NN);
    int*   rowptr  = ideg + NN;
    int*   bsum    = rowptr + NN + 8;
    int*   bofs    = bsum + 512;
    int*   rank    = bofs + 512;
    int*   csr_src = rank + NE;
    float* A       = (float*)(csr_src + NE);
    float* B       = A + (long)NN * 64;
    float* C       = B + (long)NN * 64;

    const int T = 256;

    // ---- CSR + norm build ----
    hipMemsetAsync(ideg, 0, NN * sizeof(int), stream);
    hist_rank_k<<<(NE + T - 1) / T, T, 0, stream>>>(dst, ideg, rank, NE);
    dinv_k<<<(NN + T - 1) / T, T, 0, stream>>>(ideg, dinv, NN);
    scan_reduce_k<<<NB, T, 0, stream>>>(ideg, bsum, NN);
    scan_partials_k<<<1, 512, 0, stream>>>(bsum, bofs, NB);
    scan_final_k<<<NB, T, 0, stream>>>(ideg, bofs, rowptr, NN, NE);
    fill_k<<<(NE + T - 1) / T, T, 0, stream>>>(src, dst, rank, rowptr, csr_src, NE);

    // ---- L1 GEMM: A = dinv * (x@W1)  (pre-scaled As) ----
    gemm_k<128, 16, false, true><<<(NN + 15) / 16, T, 0, stream>>>(x, nullptr, W1, dinv, A, NN);
    // ---- B = dinv * relu(S.A + b1)  (pre-scaled Bs) ----
    gather16_k<true, true><<<(NN + 3) / 4, T, 0, stream>>>(rowptr, csr_src, dinv, A, b1, B, NN);
    // ---- C = S.B  (unscaled, feeds GEMM2) ----
    gather16_k<false, false><<<(NN + 3) / 4, T, 0, stream>>>(rowptr, csr_src, dinv, B, nullptr, C, NN);
    // ---- A = dinv * relu(C@W2 + b2)  (pre-scaled, 64ch) ----
    gemm_k<16, 64, true, true><<<(NN + 3) / 4, T, 0, stream>>>(C, b2, W2, dinv, A, NN);
    // ---- B = S.A  (unscaled, 64ch) ----
    gather64_k<<<(NN + 3) / 4, T, 0, stream>>>(rowptr, csr_src, dinv, A, B, NN);
    // ---- head: out = relu(B@W3 + b3).Wfc + bfc ----
    head_k<<<2048, T, 0, stream>>>(B, W3, b3, Wfc, bfc, out, NN);
}

// Round 6
// 486.585 us; speedup vs baseline: 3.0845x; 1.0107x over previous
//
#include <hip/hip_runtime.h>

// GCN: N=100000, E=1600000, widths 128 -> 16 -> 64 -> 128 -> 1
// Round 6: head_k rebuilt with 4-node-per-wave ILP (8 independent FMA chains,
// one LDS weight read amortized over 4 nodes, float4 output store).
// Rest unchanged from round 5 (atomic-free CSR fill, weight-free gathers).

#define NN 100000
#define NE 1600000
#define NB ((NN + 255) / 256)   // 391 blocks for scans

// ---------------- histogram + rank ----------------
__global__ void hist_rank_k(const int* __restrict__ dst, int* __restrict__ ideg,
                            int* __restrict__ rank, int e) {
    int i = blockIdx.x * blockDim.x + threadIdx.x;
    if (i < e) rank[i] = atomicAdd(&ideg[dst[i]], 1);
}

__global__ void dinv_k(const int* __restrict__ ideg, float* __restrict__ dinv, int n) {
    int i = blockIdx.x * blockDim.x + threadIdx.x;
    if (i < n) dinv[i] = rsqrtf((float)ideg[i] + 1.0f);  // +1 self loop
}

// ---------------- exclusive scan (3 kernels) ----------------
__global__ void scan_reduce_k(const int* __restrict__ ideg, int* __restrict__ bsum, int n) {
    __shared__ int s[256];
    int i = blockIdx.x * 256 + threadIdx.x;
    s[threadIdx.x] = (i < n) ? ideg[i] : 0;
    __syncthreads();
    for (int off = 128; off > 0; off >>= 1) {
        if (threadIdx.x < off) s[threadIdx.x] += s[threadIdx.x + off];
        __syncthreads();
    }
    if (threadIdx.x == 0) bsum[blockIdx.x] = s[0];
}

__global__ __launch_bounds__(512) void scan_partials_k(const int* __restrict__ bsum,
                                                       int* __restrict__ bofs, int nb) {
    __shared__ int s[512];
    int t = threadIdx.x;
    int v = (t < nb) ? bsum[t] : 0;
    s[t] = v;
    __syncthreads();
    for (int off = 1; off < 512; off <<= 1) {
        int a = (t >= off) ? s[t - off] : 0;
        __syncthreads();
        s[t] += a;
        __syncthreads();
    }
    if (t < nb) bofs[t] = s[t] - v;  // exclusive
}

__global__ void scan_final_k(const int* __restrict__ ideg, const int* __restrict__ bofs,
                             int* __restrict__ rowptr, int n, int e) {
    __shared__ int s[256];
    int i = blockIdx.x * 256 + threadIdx.x;
    int t = threadIdx.x;
    int v = (i < n) ? ideg[i] : 0;
    s[t] = v;
    __syncthreads();
    for (int off = 1; off < 256; off <<= 1) {
        int a = (t >= off) ? s[t - off] : 0;
        __syncthreads();
        s[t] += a;
        __syncthreads();
    }
    int excl = s[t] - v + bofs[blockIdx.x];
    if (i < n) rowptr[i] = excl;
    if (i == 0) rowptr[n] = e;
}

// ---------------- CSR fill: no atomics ----------------
__global__ void fill_k(const int* __restrict__ src, const int* __restrict__ dst,
                       const int* __restrict__ rank, const int* __restrict__ rowptr,
                       int* __restrict__ csr_src, int e) {
    int i = blockIdx.x * blockDim.x + threadIdx.x;
    if (i < e) csr_src[rowptr[dst[i]] + rank[i]] = src[i];
}

// ---------------- dense layer: out = scale? dinv[g]*act(in@W + b) ----------------
template<int K, int M, bool BIAS_RELU, bool SCALE>
__global__ __launch_bounds__(256) void gemm_k(const float* __restrict__ in,
                                              const float* __restrict__ bias,
                                              const float* __restrict__ W,
                                              const float* __restrict__ dinv,
                                              float* __restrict__ out, int n) {
    constexpr int ROWS = 256 / M;
    constexpr int KV = K / 4;
    __shared__ float sW[K * M];
    __shared__ float sIn[ROWS][K + 4];      // +4 pad: kill 4-way bank conflict
    const int tid = threadIdx.x;
    for (int i = tid; i < K * M; i += 256) sW[i] = W[i];
    const int row0 = blockIdx.x * ROWS;
    const float4* in4 = (const float4*)in;
    for (int i = tid; i < ROWS * KV; i += 256) {
        int r = i / KV, kv = i - r * KV;
        int g = row0 + r;
        float4 v = make_float4(0.f, 0.f, 0.f, 0.f);
        if (g < n) v = in4[(long)g * KV + kv];
        ((float4*)&sIn[r][0])[kv] = v;
    }
    __syncthreads();
    const int r = tid / M, m = tid - r * M;
    const int g = row0 + r;
    if (g < n) {
        float acc = 0.0f;
#pragma unroll
        for (int k = 0; k < K; ++k) acc += sIn[r][k] * sW[k * M + m];
        if (BIAS_RELU) acc = fmaxf(acc + bias[m], 0.0f);
        if (SCALE) acc *= dinv[g];
        out[(long)g * M + m] = acc;
    }
}

// ---------------- pull-gather, 16 ch (weight-free) ----------------
template<bool BIAS_RELU, bool OUT_SCALE>
__global__ __launch_bounds__(256) void gather16_k(const int* __restrict__ rowptr,
                                                  const int* __restrict__ csr_src,
                                                  const float* __restrict__ dinv,
                                                  const float* __restrict__ hs,
                                                  const float* __restrict__ bias,
                                                  float* __restrict__ outp, int n) {
    const int g = (blockIdx.x * 256 + threadIdx.x) >> 6;
    if (g >= n) return;
    const int lane = threadIdx.x & 63;
    const int q = lane & 3;                 // float4 index within 16-ch row
    const int sub = lane >> 2;              // edge subgroup 0..15
    const float dg = dinv[g];
    const int beg = rowptr[g], end = rowptr[g + 1];
    const float4* h4 = (const float4*)hs;
    float4 acc = make_float4(0.f, 0.f, 0.f, 0.f);
    if (sub == 0) acc = h4[(long)g * 4 + q];  // self term
    for (int j0 = beg; j0 < end; j0 += 16) {
        int idx = j0 + sub;
        if (idx < end) {
            const int s = csr_src[idx];
            const float4 v = h4[(long)s * 4 + q];
            acc.x += v.x; acc.y += v.y; acc.z += v.z; acc.w += v.w;
        }
    }
#pragma unroll
    for (int m = 4; m <= 32; m <<= 1) {
        acc.x += __shfl_xor(acc.x, m, 64);
        acc.y += __shfl_xor(acc.y, m, 64);
        acc.z += __shfl_xor(acc.z, m, 64);
        acc.w += __shfl_xor(acc.w, m, 64);
    }
    if (sub == 0) {
        float4 v = make_float4(acc.x * dg, acc.y * dg, acc.z * dg, acc.w * dg);
        if (BIAS_RELU) {
            const float4 b = ((const float4*)bias)[q];
            v.x = fmaxf(v.x + b.x, 0.0f);
            v.y = fmaxf(v.y + b.y, 0.0f);
            v.z = fmaxf(v.z + b.z, 0.0f);
            v.w = fmaxf(v.w + b.w, 0.0f);
        }
        if (OUT_SCALE) { v.x *= dg; v.y *= dg; v.z *= dg; v.w *= dg; }
        ((float4*)outp)[(long)g * 4 + q] = v;
    }
}

// ---------------- pull-gather, 64 ch (weight-free, 2x unrolled) ----------------
__global__ __launch_bounds__(256) void gather64_k(const int* __restrict__ rowptr,
                                                  const int* __restrict__ csr_src,
                                                  const float* __restrict__ dinv,
                                                  const float* __restrict__ hs,
                                                  float* __restrict__ outp, int n) {
    const int g = (blockIdx.x * 256 + threadIdx.x) >> 6;
    if (g >= n) return;
    const int lane = threadIdx.x & 63;
    const int q = lane & 15;                // float4 index within 64-ch row
    const int sub = lane >> 4;              // edge subgroup 0..3
    const float dg = dinv[g];
    const int beg = rowptr[g], end = rowptr[g + 1];
    const float4* h4 = (const float4*)hs;
    float4 acc = make_float4(0.f, 0.f, 0.f, 0.f);
    if (sub == 0) acc = h4[(long)g * 16 + q];  // self term
    int j0 = beg;
    for (; j0 + 8 <= end; j0 += 8) {
        const int s0 = csr_src[j0 + sub];
        const int s1 = csr_src[j0 + 4 + sub];
        const float4 v0 = h4[(long)s0 * 16 + q];
        const float4 v1 = h4[(long)s1 * 16 + q];
        acc.x += v0.x + v1.x; acc.y += v0.y + v1.y;
        acc.z += v0.z + v1.z; acc.w += v0.w + v1.w;
    }
    for (; j0 < end; j0 += 4) {
        int idx = j0 + sub;
        if (idx < end) {
            const int s = csr_src[idx];
            const float4 v = h4[(long)s * 16 + q];
            acc.x += v.x; acc.y += v.y; acc.z += v.z; acc.w += v.w;
        }
    }
#pragma unroll
    for (int m = 16; m <= 32; m <<= 1) {
        acc.x += __shfl_xor(acc.x, m, 64);
        acc.y += __shfl_xor(acc.y, m, 64);
        acc.z += __shfl_xor(acc.z, m, 64);
        acc.w += __shfl_xor(acc.w, m, 64);
    }
    if (sub == 0) {
        ((float4*)outp)[(long)g * 16 + q] =
            make_float4(acc.x * dg, acc.y * dg, acc.z * dg, acc.w * dg);
    }
}

// ---------------- fused head, 4 nodes per wave ----------------
// out[g] = relu(aggS2[g,:]@W3 + b3) . Wfc + bfc ; N % 4 == 0 so groups are full.
__global__ __launch_bounds__(256) void head_k(const float* __restrict__ aggS2,
                                              const float* __restrict__ W3,
                                              const float* __restrict__ b3,
                                              const float* __restrict__ Wfc,
                                              const float* __restrict__ bfc,
                                              float* __restrict__ out, int n) {
    __shared__ float2 sW[64 * 64];          // sW[k*64+m] = (W3[k][m], W3[k][m+64])
    const int tid = threadIdx.x;
    for (int i = tid; i < 64 * 64; i += 256) {
        int k = i >> 6, m = i & 63;
        sW[i] = make_float2(W3[k * 128 + m], W3[k * 128 + m + 64]);
    }
    __syncthreads();
    const int lane = tid & 63;
    const int waveInBlock = tid >> 6;
    const int stride4 = gridDim.x * 4 * 4;  // waves * 4 nodes
    const float bm0 = b3[lane], bm1 = b3[lane + 64];
    const float w0 = Wfc[lane], w1 = Wfc[lane + 64];
    const float bb = bfc[0];
    for (int g0 = (blockIdx.x * 4 + waveInBlock) * 4; g0 < n; g0 += stride4) {
        const float* base = aggS2 + (long)g0 * 64 + lane;
        const float rv0 = base[0];
        const float rv1 = base[64];
        const float rv2 = base[128];
        const float rv3 = base[192];
        float a00 = 0.f, a01 = 0.f, a10 = 0.f, a11 = 0.f;
        float a20 = 0.f, a21 = 0.f, a30 = 0.f, a31 = 0.f;
#pragma unroll
        for (int k = 0; k < 64; ++k) {
            const float2 w = sW[k * 64 + lane];
            const float x0 = __shfl(rv0, k, 64);
            const float x1 = __shfl(rv1, k, 64);
            const float x2 = __shfl(rv2, k, 64);
            const float x3 = __shfl(rv3, k, 64);
            a00 = fmaf(x0, w.x, a00); a01 = fmaf(x0, w.y, a01);
            a10 = fmaf(x1, w.x, a10); a11 = fmaf(x1, w.y, a11);
            a20 = fmaf(x2, w.x, a20); a21 = fmaf(x2, w.y, a21);
            a30 = fmaf(x3, w.x, a30); a31 = fmaf(x3, w.y, a31);
        }
        float v0 = fmaxf(a00 + bm0, 0.f) * w0 + fmaxf(a01 + bm1, 0.f) * w1;
        float v1 = fmaxf(a10 + bm0, 0.f) * w0 + fmaxf(a11 + bm1, 0.f) * w1;
        float v2 = fmaxf(a20 + bm0, 0.f) * w0 + fmaxf(a21 + bm1, 0.f) * w1;
        float v3 = fmaxf(a30 + bm0, 0.f) * w0 + fmaxf(a31 + bm1, 0.f) * w1;
#pragma unroll
        for (int off = 32; off > 0; off >>= 1) {
            v0 += __shfl_down(v0, off, 64);
            v1 += __shfl_down(v1, off, 64);
            v2 += __shfl_down(v2, off, 64);
            v3 += __shfl_down(v3, off, 64);
        }
        if (lane == 0)
            ((float4*)out)[g0 >> 2] = make_float4(v0 + bb, v1 + bb, v2 + bb, v3 + bb);
    }
}

extern "C" void kernel_launch(void* const* d_in, const int* in_sizes, int n_in,
                              void* d_out, int out_size, void* d_ws, size_t ws_size,
                              hipStream_t stream) {
    const float* x    = (const float*)d_in[0];
    const int*   ei   = (const int*)d_in[1];       // [2,E]: src = ei, dst = ei+E
    const float* W1   = (const float*)d_in[2];
    const float* b1   = (const float*)d_in[3];
    const float* W2   = (const float*)d_in[4];
    const float* b2   = (const float*)d_in[5];
    const float* W3   = (const float*)d_in[6];
    const float* b3   = (const float*)d_in[7];
    const float* Wfc  = (const float*)d_in[8];
    const float* bfc  = (const float*)d_in[9];
    float* out = (float*)d_out;

    const int* src = ei;
    const int* dst = ei + NE;

    // workspace layout (4-byte elems; A offset is 16B-aligned):
    // dinv[N] | ideg[N] | rowptr[N+8] | bsum[512] | bofs[512] | rank[E]
    // | csr_src[E] | A[64N] | B[64N] | C[64N]   (~91 MB)
    float* dinv    = (float*)d_ws;
    int*   ideg    = (int*)(dinv + NN);
    int*   rowptr  = ideg + NN;
    int*   bsum    = rowptr + NN + 8;
    int*   bofs    = bsum + 512;
    int*   rank    = bofs + 512;
    int*   csr_src = rank + NE;
    float* A       = (float*)(csr_src + NE);
    float* B       = A + (long)NN * 64;
    float* C       = B + (long)NN * 64;

    const int T = 256;

    // ---- CSR + norm build ----
    hipMemsetAsync(ideg, 0, NN * sizeof(int), stream);
    hist_rank_k<<<(NE + T - 1) / T, T, 0, stream>>>(dst, ideg, rank, NE);
    dinv_k<<<(NN + T - 1) / T, T, 0, stream>>>(ideg, dinv, NN);
    scan_reduce_k<<<NB, T, 0, stream>>>(ideg, bsum, NN);
    scan_partials_k<<<1, 512, 0, stream>>>(bsum, bofs, NB);
    scan_final_k<<<NB, T, 0, stream>>>(ideg, bofs, rowptr, NN, NE);
    fill_k<<<(NE + T - 1) / T, T, 0, stream>>>(src, dst, rank, rowptr, csr_src, NE);

    // ---- L1 GEMM: A = dinv * (x@W1)  (pre-scaled As) ----
    gemm_k<128, 16, false, true><<<(NN + 15) / 16, T, 0, stream>>>(x, nullptr, W1, dinv, A, NN);
    // ---- B = dinv * relu(S.A + b1)  (pre-scaled Bs) ----
    gather16_k<true, true><<<(NN + 3) / 4, T, 0, stream>>>(rowptr, csr_src, dinv, A, b1, B, NN);
    // ---- C = S.B  (unscaled, feeds GEMM2) ----
    gather16_k<false, false><<<(NN + 3) / 4, T, 0, stream>>>(rowptr, csr_src, dinv, B, nullptr, C, NN);
    // ---- A = dinv * relu(C@W2 + b2)  (pre-scaled, 64ch) ----
    gemm_k<16, 64, true, true><<<(NN + 3) / 4, T, 0, stream>>>(C, b2, W2, dinv, A, NN);
    // ---- B = S.A  (unscaled, 64ch) ----
    gather64_k<<<(NN + 3) / 4, T, 0, stream>>>(rowptr, csr_src, dinv, A, B, NN);
    // ---- head: out = relu(B@W3 + b3).Wfc + bfc ----
    head_k<<<2048, T, 0, stream>>>(B, W3, b3, Wfc, bfc, out, NN);
}

// Round 7
// 436.670 us; speedup vs baseline: 3.4370x; 1.1143x over previous
//
#include <hip/hip_runtime.h>

// GCN: N=100000, E=1600000, widths 128 -> 16 -> 64 -> 128 -> 1
// Round 7: head_k rebuilt ZERO-LDS: W3 columns held in 128 VGPRs per lane,
// feature broadcast via v_readlane (VALU) instead of ds_bpermute (LDS pipe).
// Round-6 post-mortem showed head was LDS-pipe-bound (5 LDS ops per 8 FMAs).

#define NN 100000
#define NE 1600000
#define NB ((NN + 255) / 256)   // 391 blocks for scans

// ---------------- histogram + rank ----------------
__global__ void hist_rank_k(const int* __restrict__ dst, int* __restrict__ ideg,
                            int* __restrict__ rank, int e) {
    int i = blockIdx.x * blockDim.x + threadIdx.x;
    if (i < e) rank[i] = atomicAdd(&ideg[dst[i]], 1);
}

__global__ void dinv_k(const int* __restrict__ ideg, float* __restrict__ dinv, int n) {
    int i = blockIdx.x * blockDim.x + threadIdx.x;
    if (i < n) dinv[i] = rsqrtf((float)ideg[i] + 1.0f);  // +1 self loop
}

// ---------------- exclusive scan (3 kernels) ----------------
__global__ void scan_reduce_k(const int* __restrict__ ideg, int* __restrict__ bsum, int n) {
    __shared__ int s[256];
    int i = blockIdx.x * 256 + threadIdx.x;
    s[threadIdx.x] = (i < n) ? ideg[i] : 0;
    __syncthreads();
    for (int off = 128; off > 0; off >>= 1) {
        if (threadIdx.x < off) s[threadIdx.x] += s[threadIdx.x + off];
        __syncthreads();
    }
    if (threadIdx.x == 0) bsum[blockIdx.x] = s[0];
}

__global__ __launch_bounds__(512) void scan_partials_k(const int* __restrict__ bsum,
                                                       int* __restrict__ bofs, int nb) {
    __shared__ int s[512];
    int t = threadIdx.x;
    int v = (t < nb) ? bsum[t] : 0;
    s[t] = v;
    __syncthreads();
    for (int off = 1; off < 512; off <<= 1) {
        int a = (t >= off) ? s[t - off] : 0;
        __syncthreads();
        s[t] += a;
        __syncthreads();
    }
    if (t < nb) bofs[t] = s[t] - v;  // exclusive
}

__global__ void scan_final_k(const int* __restrict__ ideg, const int* __restrict__ bofs,
                             int* __restrict__ rowptr, int n, int e) {
    __shared__ int s[256];
    int i = blockIdx.x * 256 + threadIdx.x;
    int t = threadIdx.x;
    int v = (i < n) ? ideg[i] : 0;
    s[t] = v;
    __syncthreads();
    for (int off = 1; off < 256; off <<= 1) {
        int a = (t >= off) ? s[t - off] : 0;
        __syncthreads();
        s[t] += a;
        __syncthreads();
    }
    int excl = s[t] - v + bofs[blockIdx.x];
    if (i < n) rowptr[i] = excl;
    if (i == 0) rowptr[n] = e;
}

// ---------------- CSR fill: no atomics ----------------
__global__ void fill_k(const int* __restrict__ src, const int* __restrict__ dst,
                       const int* __restrict__ rank, const int* __restrict__ rowptr,
                       int* __restrict__ csr_src, int e) {
    int i = blockIdx.x * blockDim.x + threadIdx.x;
    if (i < e) csr_src[rowptr[dst[i]] + rank[i]] = src[i];
}

// ---------------- dense layer: out = scale? dinv[g]*act(in@W + b) ----------------
template<int K, int M, bool BIAS_RELU, bool SCALE>
__global__ __launch_bounds__(256) void gemm_k(const float* __restrict__ in,
                                              const float* __restrict__ bias,
                                              const float* __restrict__ W,
                                              const float* __restrict__ dinv,
                                              float* __restrict__ out, int n) {
    constexpr int ROWS = 256 / M;
    constexpr int KV = K / 4;
    __shared__ float sW[K * M];
    __shared__ float sIn[ROWS][K + 4];      // +4 pad: kill 4-way bank conflict
    const int tid = threadIdx.x;
    for (int i = tid; i < K * M; i += 256) sW[i] = W[i];
    const int row0 = blockIdx.x * ROWS;
    const float4* in4 = (const float4*)in;
    for (int i = tid; i < ROWS * KV; i += 256) {
        int r = i / KV, kv = i - r * KV;
        int g = row0 + r;
        float4 v = make_float4(0.f, 0.f, 0.f, 0.f);
        if (g < n) v = in4[(long)g * KV + kv];
        ((float4*)&sIn[r][0])[kv] = v;
    }
    __syncthreads();
    const int r = tid / M, m = tid - r * M;
    const int g = row0 + r;
    if (g < n) {
        float acc = 0.0f;
#pragma unroll
        for (int k = 0; k < K; ++k) acc += sIn[r][k] * sW[k * M + m];
        if (BIAS_RELU) acc = fmaxf(acc + bias[m], 0.0f);
        if (SCALE) acc *= dinv[g];
        out[(long)g * M + m] = acc;
    }
}

// ---------------- pull-gather, 16 ch (weight-free) ----------------
template<bool BIAS_RELU, bool OUT_SCALE>
__global__ __launch_bounds__(256) void gather16_k(const int* __restrict__ rowptr,
                                                  const int* __restrict__ csr_src,
                                                  const float* __restrict__ dinv,
                                                  const float* __restrict__ hs,
                                                  const float* __restrict__ bias,
                                                  float* __restrict__ outp, int n) {
    const int g = (blockIdx.x * 256 + threadIdx.x) >> 6;
    if (g >= n) return;
    const int lane = threadIdx.x & 63;
    const int q = lane & 3;                 // float4 index within 16-ch row
    const int sub = lane >> 2;              // edge subgroup 0..15
    const float dg = dinv[g];
    const int beg = rowptr[g], end = rowptr[g + 1];
    const float4* h4 = (const float4*)hs;
    float4 acc = make_float4(0.f, 0.f, 0.f, 0.f);
    if (sub == 0) acc = h4[(long)g * 4 + q];  // self term
    for (int j0 = beg; j0 < end; j0 += 16) {
        int idx = j0 + sub;
        if (idx < end) {
            const int s = csr_src[idx];
            const float4 v = h4[(long)s * 4 + q];
            acc.x += v.x; acc.y += v.y; acc.z += v.z; acc.w += v.w;
        }
    }
#pragma unroll
    for (int m = 4; m <= 32; m <<= 1) {
        acc.x += __shfl_xor(acc.x, m, 64);
        acc.y += __shfl_xor(acc.y, m, 64);
        acc.z += __shfl_xor(acc.z, m, 64);
        acc.w += __shfl_xor(acc.w, m, 64);
    }
    if (sub == 0) {
        float4 v = make_float4(acc.x * dg, acc.y * dg, acc.z * dg, acc.w * dg);
        if (BIAS_RELU) {
            const float4 b = ((const float4*)bias)[q];
            v.x = fmaxf(v.x + b.x, 0.0f);
            v.y = fmaxf(v.y + b.y, 0.0f);
            v.z = fmaxf(v.z + b.z, 0.0f);
            v.w = fmaxf(v.w + b.w, 0.0f);
        }
        if (OUT_SCALE) { v.x *= dg; v.y *= dg; v.z *= dg; v.w *= dg; }
        ((float4*)outp)[(long)g * 4 + q] = v;
    }
}

// ---------------- pull-gather, 64 ch (weight-free, 2x unrolled) ----------------
__global__ __launch_bounds__(256) void gather64_k(const int* __restrict__ rowptr,
                                                  const int* __restrict__ csr_src,
                                                  const float* __restrict__ dinv,
                                                  const float* __restrict__ hs,
                                                  float* __restrict__ outp, int n) {
    const int g = (blockIdx.x * 256 + threadIdx.x) >> 6;
    if (g >= n) return;
    const int lane = threadIdx.x & 63;
    const int q = lane & 15;                // float4 index within 64-ch row
    const int sub = lane >> 4;              // edge subgroup 0..3
    const float dg = dinv[g];
    const int beg = rowptr[g], end = rowptr[g + 1];
    const float4* h4 = (const float4*)hs;
    float4 acc = make_float4(0.f, 0.f, 0.f, 0.f);
    if (sub == 0) acc = h4[(long)g * 16 + q];  // self term
    int j0 = beg;
    for (; j0 + 8 <= end; j0 += 8) {
        const int s0 = csr_src[j0 + sub];
        const int s1 = csr_src[j0 + 4 + sub];
        const float4 v0 = h4[(long)s0 * 16 + q];
        const float4 v1 = h4[(long)s1 * 16 + q];
        acc.x += v0.x + v1.x; acc.y += v0.y + v1.y;
        acc.z += v0.z + v1.z; acc.w += v0.w + v1.w;
    }
    for (; j0 < end; j0 += 4) {
        int idx = j0 + sub;
        if (idx < end) {
            const int s = csr_src[idx];
            const float4 v = h4[(long)s * 16 + q];
            acc.x += v.x; acc.y += v.y; acc.z += v.z; acc.w += v.w;
        }
    }
#pragma unroll
    for (int m = 16; m <= 32; m <<= 1) {
        acc.x += __shfl_xor(acc.x, m, 64);
        acc.y += __shfl_xor(acc.y, m, 64);
        acc.z += __shfl_xor(acc.z, m, 64);
        acc.w += __shfl_xor(acc.w, m, 64);
    }
    if (sub == 0) {
        ((float4*)outp)[(long)g * 16 + q] =
            make_float4(acc.x * dg, acc.y * dg, acc.z * dg, acc.w * dg);
    }
}

// ---------------- fused head, zero-LDS inner loop ----------------
// Lane L owns output channels (L, L+64); their W3 columns live in 128 VGPRs.
// Feature broadcast via v_readlane (constant lane index from unrolled loop).
// out[g] = relu(aggS2[g,:]@W3 + b3) . Wfc + bfc ; N % 4 == 0.
__device__ __forceinline__ float bcast_lane(float v, int k) {
    return __int_as_float(__builtin_amdgcn_readlane(__float_as_int(v), k));
}

__global__ __launch_bounds__(256) void head_k(const float* __restrict__ aggS2,
                                              const float* __restrict__ W3,
                                              const float* __restrict__ b3,
                                              const float* __restrict__ Wfc,
                                              const float* __restrict__ bfc,
                                              float* __restrict__ out, int n) {
    const int lane = threadIdx.x & 63;
    const int wid = blockIdx.x * 4 + (threadIdx.x >> 6);
    const int nWaves = gridDim.x * 4;
    // per-lane W3 columns (coalesced loads; 32 KB set, L2-hot)
    float w0[64], w1[64];
#pragma unroll
    for (int k = 0; k < 64; ++k) {
        w0[k] = W3[k * 128 + lane];
        w1[k] = W3[k * 128 + lane + 64];
    }
    const float bm0 = b3[lane], bm1 = b3[lane + 64];
    const float wf0 = Wfc[lane], wf1 = Wfc[lane + 64];
    const float bb = bfc[0];
    for (int g0 = wid * 4; g0 < n; g0 += nWaves * 4) {
        const float* base = aggS2 + (long)g0 * 64 + lane;
        const float rv0 = base[0];
        const float rv1 = base[64];
        const float rv2 = base[128];
        const float rv3 = base[192];
        float a00 = 0.f, a01 = 0.f, a10 = 0.f, a11 = 0.f;
        float a20 = 0.f, a21 = 0.f, a30 = 0.f, a31 = 0.f;
#pragma unroll
        for (int k = 0; k < 64; ++k) {
            const float x0 = bcast_lane(rv0, k);
            const float x1 = bcast_lane(rv1, k);
            const float x2 = bcast_lane(rv2, k);
            const float x3 = bcast_lane(rv3, k);
            a00 = fmaf(x0, w0[k], a00); a01 = fmaf(x0, w1[k], a01);
            a10 = fmaf(x1, w0[k], a10); a11 = fmaf(x1, w1[k], a11);
            a20 = fmaf(x2, w0[k], a20); a21 = fmaf(x2, w1[k], a21);
            a30 = fmaf(x3, w0[k], a30); a31 = fmaf(x3, w1[k], a31);
        }
        float v0 = fmaxf(a00 + bm0, 0.f) * wf0 + fmaxf(a01 + bm1, 0.f) * wf1;
        float v1 = fmaxf(a10 + bm0, 0.f) * wf0 + fmaxf(a11 + bm1, 0.f) * wf1;
        float v2 = fmaxf(a20 + bm0, 0.f) * wf0 + fmaxf(a21 + bm1, 0.f) * wf1;
        float v3 = fmaxf(a30 + bm0, 0.f) * wf0 + fmaxf(a31 + bm1, 0.f) * wf1;
#pragma unroll
        for (int off = 32; off > 0; off >>= 1) {
            v0 += __shfl_down(v0, off, 64);
            v1 += __shfl_down(v1, off, 64);
            v2 += __shfl_down(v2, off, 64);
            v3 += __shfl_down(v3, off, 64);
        }
        if (lane == 0)
            ((float4*)out)[g0 >> 2] = make_float4(v0 + bb, v1 + bb, v2 + bb, v3 + bb);
    }
}

extern "C" void kernel_launch(void* const* d_in, const int* in_sizes, int n_in,
                              void* d_out, int out_size, void* d_ws, size_t ws_size,
                              hipStream_t stream) {
    const float* x    = (const float*)d_in[0];
    const int*   ei   = (const int*)d_in[1];       // [2,E]: src = ei, dst = ei+E
    const float* W1   = (const float*)d_in[2];
    const float* b1   = (const float*)d_in[3];
    const float* W2   = (const float*)d_in[4];
    const float* b2   = (const float*)d_in[5];
    const float* W3   = (const float*)d_in[6];
    const float* b3   = (const float*)d_in[7];
    const float* Wfc  = (const float*)d_in[8];
    const float* bfc  = (const float*)d_in[9];
    float* out = (float*)d_out;

    const int* src = ei;
    const int* dst = ei + NE;

    // workspace layout (4-byte elems; A offset is 16B-aligned):
    // dinv[N] | ideg[N] | rowptr[N+8] | bsum[512] | bofs[512] | rank[E]
    // | csr_src[E] | A[64N] | B[64N] | C[64N]   (~91 MB)
    float* dinv    = (float*)d_ws;
    int*   ideg    = (int*)(dinv + NN);
    int*   rowptr  = ideg + NN;
    int*   bsum    = rowptr + NN + 8;
    int*   bofs    = bsum + 512;
    int*   rank    = bofs + 512;
    int*   csr_src = rank + NE;
    float* A       = (float*)(csr_src + NE);
    float* B       = A + (long)NN * 64;
    float* C       = B + (long)NN * 64;

    const int T = 256;

    // ---- CSR + norm build ----
    hipMemsetAsync(ideg, 0, NN * sizeof(int), stream);
    hist_rank_k<<<(NE + T - 1) / T, T, 0, stream>>>(dst, ideg, rank, NE);
    dinv_k<<<(NN + T - 1) / T, T, 0, stream>>>(ideg, dinv, NN);
    scan_reduce_k<<<NB, T, 0, stream>>>(ideg, bsum, NN);
    scan_partials_k<<<1, 512, 0, stream>>>(bsum, bofs, NB);
    scan_final_k<<<NB, T, 0, stream>>>(ideg, bofs, rowptr, NN, NE);
    fill_k<<<(NE + T - 1) / T, T, 0, stream>>>(src, dst, rank, rowptr, csr_src, NE);

    // ---- L1 GEMM: A = dinv * (x@W1)  (pre-scaled As) ----
    gemm_k<128, 16, false, true><<<(NN + 15) / 16, T, 0, stream>>>(x, nullptr, W1, dinv, A, NN);
    // ---- B = dinv * relu(S.A + b1)  (pre-scaled Bs) ----
    gather16_k<true, true><<<(NN + 3) / 4, T, 0, stream>>>(rowptr, csr_src, dinv, A, b1, B, NN);
    // ---- C = S.B  (unscaled, feeds GEMM2) ----
    gather16_k<false, false><<<(NN + 3) / 4, T, 0, stream>>>(rowptr, csr_src, dinv, B, nullptr, C, NN);
    // ---- A = dinv * relu(C@W2 + b2)  (pre-scaled, 64ch) ----
    gemm_k<16, 64, true, true><<<(NN + 3) / 4, T, 0, stream>>>(C, b2, W2, dinv, A, NN);
    // ---- B = S.A  (unscaled, 64ch) ----
    gather64_k<<<(NN + 3) / 4, T, 0, stream>>>(rowptr, csr_src, dinv, A, B, NN);
    // ---- head: out = relu(B@W3 + b3).Wfc + bfc ----
    head_k<<<1024, T, 0, stream>>>(B, W3, b3, Wfc, bfc, out, NN);
}